// Round 3
// baseline (1245.154 us; speedup 1.0000x reference)
//
#include <hip/hip_runtime.h>

#define KSIZE 7
#define NEG_INF (-1e30f)
#define TILE_W 128
#define TILE_H 32
#define HALO_L 4                     // left halo padded to 4 for float4 alignment
#define REG_W 136                    // TILE_W + 4 left + 4 right (data columns)
#define REG_H 38                     // TILE_H + 6
#define LDS_STRIDE 144               // pad 136->144: half-wave row delta (2 rows
                                     // = 288 dwords) stays = 0 mod 32 banks
#define IMG_H 512
#define IMG_W 512
#define N_VEC4 (LDS_STRIDE / 4)      // 36 float4 per padded row
#define TOT_VEC4 (REG_H * N_VEC4)    // 1368 float4 slots

// <2 x float> — fadd lowers to v_pk_add_f32 on gfx90a+ (packed fp32 ops)
typedef float pk2 __attribute__((ext_vector_type(2)));

// fmaxf(a, fmaxf(b, c)) -> v_max3_f32
#define M3(a, b, c) fmaxf((a), fmaxf((b), (c)))

static __device__ __forceinline__ pk2 mk2(float a, float b) {
    pk2 r; r.x = a; r.y = b; return r;
}

// One filter-row contribution to one output: taps t_j = v[1+l+j] + f[j].
// Pairs (j, j+1) for j = 0,2,4 are packed adds; j=6 scalar. Max tree identical
// in value to the scalar version (max is exactly associative/commutative).
static __device__ __forceinline__ float dil_body(float acc, pk2 a, pk2 b, pk2 c,
                                                 float t6v, pk2 f01, pk2 f23,
                                                 pk2 f45, float f6) {
    const pk2 t01 = a + f01;          // v_pk_add_f32
    const pk2 t23 = b + f23;
    const pk2 t45 = c + f45;
    const float t6 = t6v + f6;
    const float u = M3(t01.x, t01.y, t23.x);
    const float w = M3(t23.y, t45.x, t45.y);
    const float z = M3(acc, t6, u);
    return fmaxf(z, w);
}

__global__ __launch_bounds__(512, 8)  // 8 waves/EU -> 4 blocks/CU, VGPR <= 64
void GrayscaleDilation2D_kernel(const float* __restrict__ img,
                                const float* __restrict__ filt,
                                float* __restrict__ out) {
    __shared__ float tile[REG_H * LDS_STRIDE];

    const int plane = blockIdx.z;
    const int x0 = blockIdx.x * TILE_W;
    const int y0 = blockIdx.y * TILE_H;
    const float* __restrict__ src = img + (size_t)plane * IMG_H * IMG_W;
    float* __restrict__ dst = out + (size_t)plane * IMG_H * IMG_W;

    const int tx = threadIdx.x;  // 0..31
    const int ty = threadIdx.y;  // 0..15
    const int t = ty * 32 + tx;  // 0..511

    // Filter prepacked as float2 pairs (f[i][2p], f[i][2p+1]) + scalar f[i][6].
    // Uniform addresses + constant indices -> scalar loads, SGPR pairs.
    pk2 fp[KSIZE][3];
    float f6[KSIZE];
#pragma unroll
    for (int i = 0; i < KSIZE; ++i) {
        const float* fr = filt + i * KSIZE;
        fp[i][0] = mk2(fr[0], fr[1]);
        fp[i][1] = mk2(fr[2], fr[3]);
        fp[i][2] = mk2(fr[4], fr[5]);
        f6[i] = fr[6];
    }

    // Stage (REG_H x LDS_STRIDE) region into LDS as aligned float4.
    // Pad columns (c4=34,35) stage harmlessly (never read by taps).
#pragma unroll
    for (int it = 0; it < 3; ++it) {
        const int idx = t + it * 512;
        if (idx < TOT_VEC4) {
            const int r  = idx / N_VEC4;
            const int c4 = idx - r * N_VEC4;
            const int gy = y0 - 3 + r;
            const int gx = x0 - HALO_L + c4 * 4;
            float4 v4 = make_float4(NEG_INF, NEG_INF, NEG_INF, NEG_INF);
            if ((unsigned)gy < IMG_H && (unsigned)gx < IMG_W)
                v4 = *(const float4*)&src[gy * IMG_W + gx];
            *(float4*)&tile[r * LDS_STRIDE + c4 * 4] = v4;
        }
    }
    __syncthreads();

    // Each thread: 4 wide x 2 tall. rows y0+ty*2+o, cols x0+tx*4+l.
    float acc[2][4];
#pragma unroll
    for (int o = 0; o < 2; ++o)
#pragma unroll
        for (int l = 0; l < 4; ++l) acc[o][l] = NEG_INF;

    const int row0 = ty * 2;
    const int col0 = tx * 4;

#pragma unroll
    for (int r = 0; r < 8; ++r) {
        const float* rp = &tile[(row0 + r) * LDS_STRIDE + col0];
        // Natural even pairs e[m] = (v[2m], v[2m+1]): 5x ds_read_b64
        // (2-way bank aliasing, measured free; R2 pattern -> 0 conflicts).
        const pk2 e0 = *(const pk2*)(rp);
        const pk2 e1 = *(const pk2*)(rp + 2);
        const pk2 e2 = *(const pk2*)(rp + 4);
        const pk2 e3 = *(const pk2*)(rp + 6);
        const pk2 e4 = *(const pk2*)(rp + 8);
        const float v10 = rp[10];               // only scalar tap of last slot
        // Odd pairs q[m] = (v[2m+1], v[2m+2]), shared by both o-bodies.
        const pk2 q0 = __builtin_shufflevector(e0, e1, 1, 2);
        const pk2 q1 = __builtin_shufflevector(e1, e2, 1, 2);
        const pk2 q2 = __builtin_shufflevector(e2, e3, 1, 2);
        const pk2 q3 = __builtin_shufflevector(e3, e4, 1, 2);

        const int omin = (r - 6 < 0) ? 0 : r - 6;
        const int omax = (r < 1) ? r : 1;
#pragma unroll
        for (int o = 0; o < 2; ++o) {
            if (o < omin || o > omax) continue;  // static after unroll
            const int i = r - o;                 // filter row
            // l=0: v1..v7  -> q0,q1,q2, t6=v7=e3.y
            acc[o][0] = dil_body(acc[o][0], q0, q1, q2, e3.y,
                                 fp[i][0], fp[i][1], fp[i][2], f6[i]);
            // l=1: v2..v8  -> e1,e2,e3, t6=v8=e4.x
            acc[o][1] = dil_body(acc[o][1], e1, e2, e3, e4.x,
                                 fp[i][0], fp[i][1], fp[i][2], f6[i]);
            // l=2: v3..v9  -> q1,q2,q3, t6=v9=e4.y
            acc[o][2] = dil_body(acc[o][2], q1, q2, q3, e4.y,
                                 fp[i][0], fp[i][1], fp[i][2], f6[i]);
            // l=3: v4..v10 -> e2,e3,e4, t6=v10
            acc[o][3] = dil_body(acc[o][3], e2, e3, e4, v10,
                                 fp[i][0], fp[i][1], fp[i][2], f6[i]);
        }
    }

#pragma unroll
    for (int o = 0; o < 2; ++o) {
        float4 res = make_float4(acc[o][0], acc[o][1], acc[o][2], acc[o][3]);
        *(float4*)&dst[(size_t)(y0 + row0 + o) * IMG_W + (x0 + col0)] = res;
    }
}

extern "C" void kernel_launch(void* const* d_in, const int* in_sizes, int n_in,
                              void* d_out, int out_size, void* d_ws, size_t ws_size,
                              hipStream_t stream) {
    const float* img  = (const float*)d_in[0];
    const float* filt = (const float*)d_in[1];
    float* out = (float*)d_out;

    const int planes = in_sizes[0] / (IMG_H * IMG_W);  // B*C = 128
    dim3 grid(IMG_W / TILE_W, IMG_H / TILE_H, planes);
    dim3 block(32, 16);
    hipLaunchKernelGGL(GrayscaleDilation2D_kernel, grid, block, 0, stream,
                       img, filt, out);
}

// Round 4
// 256.067 us; speedup vs baseline: 4.8626x; 4.8626x over previous
//
#include <hip/hip_runtime.h>

#define KSIZE 7
#define NEG_INF (-1e30f)
#define IMG_H 512
#define IMG_W 512
#define TILE_W 128
#define CHUNK 16                   // input rows staged per step
#define RING 64                    // LDS ring rows (power of two, holds 4 chunks)
#define LDS_STRIDE 144             // dwords per ring row (R2-proven conflict-free)
#define NXV4 34                    // data float4 per row (136 cols = 128 + 2*4 halo)
#define CHUNK_V4 (CHUNK * NXV4)    // 544 float4 per chunk
#define STEPS 16                   // 16 steps x 16 rows = 256-row stripe per block

// <2 x float> — fadd lowers to v_pk_add_f32 on gfx90a+ (packed fp32 ops)
typedef float pk2 __attribute__((ext_vector_type(2)));

// fmaxf(a, fmaxf(b, c)) -> v_max3_f32
#define M3(a, b, c) fmaxf((a), fmaxf((b), (c)))

static __device__ __forceinline__ pk2 mk2(float a, float b) {
    pk2 r; r.x = a; r.y = b; return r;
}

// One filter-row contribution to one output: taps t_j = v[1+l+j] + f[j].
// Pairs (j, j+1) for j = 0,2,4 packed; j=6 scalar. Max tree exactly equal in
// value to the scalar version (max is associative/commutative).
static __device__ __forceinline__ float dil_body(float acc, pk2 a, pk2 b, pk2 c,
                                                 float t6v, pk2 f01, pk2 f23,
                                                 pk2 f45, float f6) {
    const pk2 t01 = a + f01;          // v_pk_add_f32
    const pk2 t23 = b + f23;
    const pk2 t45 = c + f45;
    const float t6 = t6v + f6;
    const float u = M3(t01.x, t01.y, t23.x);
    const float w = M3(t23.y, t45.x, t45.y);
    const float z = M3(acc, t6, u);
    return fmaxf(z, w);
}

// NOTE: no min-waves launch bound — R3 showed forcing it causes catastrophic
// spill (VGPR 32, FETCH 2 GB). Residency here is LDS-capped at 4 blocks/CU,
// whose VGPR budget (256/wave) the kernel fits trivially.
__global__ __launch_bounds__(128)
void GrayscaleDilation2D_kernel(const float* __restrict__ img,
                                const float* __restrict__ filt,
                                float* __restrict__ out) {
    __shared__ float ring[RING * LDS_STRIDE];   // 36864 B -> 4 blocks/CU

    const int plane = blockIdx.z;
    const int x0 = blockIdx.x * TILE_W;
    const int c0 = blockIdx.y * STEPS;          // first chunk of this stripe
    // Staging guard: rows >= ylim are never read by this stripe -> skip fetch.
    const int ylim = blockIdx.y ? IMG_H : (256 + 3);
    const float* __restrict__ src = img + (size_t)plane * IMG_H * IMG_W;
    float* __restrict__ dst = out + (size_t)plane * IMG_H * IMG_W;

    const int tx = threadIdx.x;   // 0..31
    const int ty = threadIdx.y;   // 0..3
    const int t  = ty * 32 + tx;  // 0..127

    // Filter prepacked as pairs + scalar; uniform const loads -> SGPRs.
    pk2 fp[KSIZE][3];
    float f6[KSIZE];
#pragma unroll
    for (int i = 0; i < KSIZE; ++i) {
        const float* fr = filt + i * KSIZE;
        fp[i][0] = mk2(fr[0], fr[1]);
        fp[i][1] = mk2(fr[2], fr[3]);
        fp[i][2] = mk2(fr[4], fr[5]);
        f6[i] = fr[6];
    }

    // In-flight staging registers (T14 issue-early / write-late).
    float4 stage[5];

    // Issue global loads for chunk k into stage[] (guarded; OOB -> NEG_INF).
    // gx multiple of 4 and 512%4==0 -> each float4 fully in or fully out.
    auto load_chunk = [&](int k) {
#pragma unroll
        for (int it = 0; it < 5; ++it) {
            const int idx = t + it * 128;
            float4 v = make_float4(NEG_INF, NEG_INF, NEG_INF, NEG_INF);
            if (idx < CHUNK_V4) {
                const int r  = idx / NXV4;          // magic-mul div
                const int c4 = idx - r * NXV4;
                const int gy = k * CHUNK + r;
                const int gx = x0 - 4 + c4 * 4;
                if ((unsigned)gy < (unsigned)ylim && (unsigned)gx < IMG_W)
                    v = *(const float4*)&src[gy * IMG_W + gx];
            }
            stage[it] = v;
        }
    };

    // Write stage[] into ring slots of chunk k (slot base = (k&3)*16, scalar).
    auto write_chunk = [&](int k) {
        const int kb = (k & 3) * CHUNK;
#pragma unroll
        for (int it = 0; it < 5; ++it) {
            const int idx = t + it * 128;
            if (idx < CHUNK_V4) {
                const int r  = idx / NXV4;
                const int c4 = idx - r * NXV4;
                *(float4*)&ring[(kb + r) * LDS_STRIDE + c4 * 4] = stage[it];
            }
        }
    };

    // Prologue: ring <- chunks c0-1 (top halo / other stripe), c0, c0+1;
    // loads for c0+2 left in flight across step 0's compute.
    load_chunk(c0 - 1); write_chunk(c0 - 1);
    load_chunk(c0);     write_chunk(c0);
    load_chunk(c0 + 1); write_chunk(c0 + 1);
    load_chunk(c0 + 2);
    __syncthreads();

    const int row0 = ty * 4;
    const int col0 = tx * 4;

    for (int s = 0; s < STEPS; ++s) {
        const int c = c0 + s;
        const int ybase = c * CHUNK;

        float acc[4][4];
#pragma unroll
        for (int o = 0; o < 4; ++o)
#pragma unroll
            for (int l = 0; l < 4; ++l) acc[o][l] = NEG_INF;

#pragma unroll
        for (int r = 0; r < 10; ++r) {
            const int slot = (ybase + row0 - 3 + r) & (RING - 1);
            const float* rp = &ring[slot * LDS_STRIDE + col0];
            // Even pairs: 5x ds_read_b64 + 1 b32 (R2 pattern, measured 0 confl).
            const pk2 e0 = *(const pk2*)(rp);
            const pk2 e1 = *(const pk2*)(rp + 2);
            const pk2 e2 = *(const pk2*)(rp + 4);
            const pk2 e3 = *(const pk2*)(rp + 6);
            const pk2 e4 = *(const pk2*)(rp + 8);
            const float v10 = rp[10];
            // Odd pairs, shared by all o-bodies of this window row.
            const pk2 q0 = __builtin_shufflevector(e0, e1, 1, 2);
            const pk2 q1 = __builtin_shufflevector(e1, e2, 1, 2);
            const pk2 q2 = __builtin_shufflevector(e2, e3, 1, 2);
            const pk2 q3 = __builtin_shufflevector(e3, e4, 1, 2);

            const int omin = (r - 6 < 0) ? 0 : r - 6;
            const int omax = (r < 3) ? r : 3;
#pragma unroll
            for (int o = 0; o < 4; ++o) {
                if (o < omin || o > omax) continue;  // static after unroll
                const int i = r - o;                 // filter row
                acc[o][0] = dil_body(acc[o][0], q0, q1, q2, e3.y,
                                     fp[i][0], fp[i][1], fp[i][2], f6[i]);
                acc[o][1] = dil_body(acc[o][1], e1, e2, e3, e4.x,
                                     fp[i][0], fp[i][1], fp[i][2], f6[i]);
                acc[o][2] = dil_body(acc[o][2], q1, q2, q3, e4.y,
                                     fp[i][0], fp[i][1], fp[i][2], f6[i]);
                acc[o][3] = dil_body(acc[o][3], e2, e3, e4, v10,
                                     fp[i][0], fp[i][1], fp[i][2], f6[i]);
            }
        }

        const int gy0 = ybase + row0;
#pragma unroll
        for (int o = 0; o < 4; ++o) {
            float4 res = make_float4(acc[o][0], acc[o][1], acc[o][2], acc[o][3]);
            *(float4*)&dst[(size_t)(gy0 + o) * IMG_W + (x0 + col0)] = res;
        }

        // Write target = slots of dead chunk c-2; step-s readers touch only
        // c-1,c,c+1, so no barrier needed before the write. One barrier/step.
        if (s < STEPS - 1) write_chunk(c + 2);
        if (s < STEPS - 2) load_chunk(c + 3);   // consumed end of next step
        if (s < STEPS - 1) __syncthreads();
    }
}

extern "C" void kernel_launch(void* const* d_in, const int* in_sizes, int n_in,
                              void* d_out, int out_size, void* d_ws, size_t ws_size,
                              hipStream_t stream) {
    const float* img  = (const float*)d_in[0];
    const float* filt = (const float*)d_in[1];
    float* out = (float*)d_out;

    const int planes = in_sizes[0] / (IMG_H * IMG_W);  // B*C = 128
    dim3 grid(IMG_W / TILE_W, 2, planes);              // 4 x 2 x 128 = 1024
    dim3 block(32, 4);
    hipLaunchKernelGGL(GrayscaleDilation2D_kernel, grid, block, 0, stream,
                       img, filt, out);
}